// Round 1
// baseline (969.888 us; speedup 1.0000x reference)
//
#include <hip/hip_runtime.h>

// ConstructBaselineSuperEdge: B=8192, NM=ND=32 (N=64), NODE_F=EDGE_F=HID=256.
//
// Algebraic rewrite (exact):
//   scores_n = (e_n . (Wk @ q) + q.bk) / 16          -- avoids k projection
//   local    = (sum_n attn_n * e_n) @ Wv + bv        -- avoids v projection
// => kernel is HBM-bound on the 1.04 GB of neighbor features, read once.

constexpr int G = 8;   // batch elements per block

__global__ __launch_bounds__(256, 4)
void superedge_fused(const float* __restrict__ mnode0,
                     const float* __restrict__ mnode1,
                     const float* __restrict__ dnode0,
                     const float* __restrict__ dnode1,
                     const float* __restrict__ mrel0,
                     const float* __restrict__ drel0,
                     const float* __restrict__ W_edge,
                     const float* __restrict__ b_edge,
                     const float* __restrict__ Wq,
                     const float* __restrict__ bq,
                     const float* __restrict__ Wk,
                     const float* __restrict__ bk,
                     const float* __restrict__ Wv,
                     const float* __restrict__ bv,
                     float* __restrict__ out)
{
    __shared__ float sA[G * 512];   // pre_md, later reused: attn-weighted neighbor sum
    __shared__ float sK[G * 512];   // qk = Wk @ q  ([0:256]=rel rows, [256:512]=node rows)
    __shared__ float sC[G * 256];   // edge_emb, later reused: q

    const int t  = threadIdx.x;      // 256 threads = 4 waves
    const int b0 = blockIdx.x * G;

    // ---------- Phase 1: stage pre_md = [mnode0 || dnode0] ----------
    {
        const float4* m4 = reinterpret_cast<const float4*>(mnode0);
        const float4* d4 = reinterpret_cast<const float4*>(dnode0);
        float4* A4 = reinterpret_cast<float4*>(sA);
        #pragma unroll
        for (int idx = t; idx < G * 128; idx += 256) {
            const int g  = idx >> 7;
            const int i4 = idx & 127;
            A4[g * 128 + i4] = (i4 < 64) ? m4[(b0 + g) * 64 + i4]
                                         : d4[(b0 + g) * 64 + (i4 - 64)];
        }
    }
    __syncthreads();

    // ---------- Phase 2: edge_emb = relu(pre_md @ W_edge + b_edge) ----------
    // thread t owns output column t; LDS reads are wave-uniform (broadcast).
    float acc[G];
    #pragma unroll
    for (int g = 0; g < G; ++g) acc[g] = 0.f;
    #pragma unroll 4
    for (int i4 = 0; i4 < 128; ++i4) {
        const float w0 = W_edge[(i4 * 4 + 0) * 256 + t];
        const float w1 = W_edge[(i4 * 4 + 1) * 256 + t];
        const float w2 = W_edge[(i4 * 4 + 2) * 256 + t];
        const float w3 = W_edge[(i4 * 4 + 3) * 256 + t];
        #pragma unroll
        for (int g = 0; g < G; ++g) {
            const float4 a = reinterpret_cast<const float4*>(sA)[g * 128 + i4];
            acc[g] = fmaf(a.x, w0, fmaf(a.y, w1, fmaf(a.z, w2, fmaf(a.w, w3, acc[g]))));
        }
    }
    {
        const float be = b_edge[t];
        #pragma unroll
        for (int g = 0; g < G; ++g) {
            float e = acc[g] + be;
            e = e > 0.f ? e : 0.f;
            out[(size_t)(b0 + g) * 512 + t] = e;   // output[:, 0:256]
            sC[g * 256 + t] = e;
        }
    }
    __syncthreads();

    // ---------- Phase 3: q = edge_emb @ Wq + bq ----------
    #pragma unroll
    for (int g = 0; g < G; ++g) acc[g] = 0.f;
    #pragma unroll 4
    for (int i4 = 0; i4 < 64; ++i4) {
        const float w0 = Wq[(i4 * 4 + 0) * 256 + t];
        const float w1 = Wq[(i4 * 4 + 1) * 256 + t];
        const float w2 = Wq[(i4 * 4 + 2) * 256 + t];
        const float w3 = Wq[(i4 * 4 + 3) * 256 + t];
        #pragma unroll
        for (int g = 0; g < G; ++g) {
            const float4 a = reinterpret_cast<const float4*>(sC)[g * 64 + i4];
            acc[g] = fmaf(a.x, w0, fmaf(a.y, w1, fmaf(a.z, w2, fmaf(a.w, w3, acc[g]))));
        }
    }
    const float bqv = bq[t];
    __syncthreads();   // all reads of edge_emb done before overwriting sC with q
    #pragma unroll
    for (int g = 0; g < G; ++g) sC[g * 256 + t] = acc[g] + bqv;
    __syncthreads();

    // ---------- Phase 4: qk = Wk @ q (rows i=t and i=t+256 per thread) ----------
    {
        float k0[G], k1[G];
        #pragma unroll
        for (int g = 0; g < G; ++g) { k0[g] = 0.f; k1[g] = 0.f; }
        const float4* Wk4 = reinterpret_cast<const float4*>(Wk);
        #pragma unroll 4
        for (int jj = 0; jj < 64; ++jj) {
            const float4 w0 = Wk4[t * 64 + jj];
            const float4 w1 = Wk4[(t + 256) * 64 + jj];
            #pragma unroll
            for (int g = 0; g < G; ++g) {
                const float4 qv = reinterpret_cast<const float4*>(sC)[g * 64 + jj];
                k0[g] = fmaf(w0.x, qv.x, fmaf(w0.y, qv.y, fmaf(w0.z, qv.z, fmaf(w0.w, qv.w, k0[g]))));
                k1[g] = fmaf(w1.x, qv.x, fmaf(w1.y, qv.y, fmaf(w1.z, qv.z, fmaf(w1.w, qv.w, k1[g]))));
            }
        }
        #pragma unroll
        for (int g = 0; g < G; ++g) {
            sK[g * 512 + t]       = k0[g];   // rel rows
            sK[g * 512 + 256 + t] = k1[g];   // node rows
        }
    }
    __syncthreads();

    // ---------- Phase 5: streaming attention (one global read per element) ----------
    {
        const int wave = t >> 6;
        const int lane = t & 63;
        #pragma unroll
        for (int gg = 0; gg < 2; ++gg) {
            const int g  = wave * 2 + gg;
            const int bg = b0 + g;

            // sb = q . bk  (wave reduction)
            const float4 qv  = reinterpret_cast<const float4*>(sC + g * 256)[lane];
            const float4 bkv = reinterpret_cast<const float4*>(bk)[lane];
            float sb = qv.x * bkv.x + qv.y * bkv.y + qv.z * bkv.z + qv.w * bkv.w;
            #pragma unroll
            for (int off = 32; off >= 1; off >>= 1) sb += __shfl_xor(sb, off);

            const float4 kr = reinterpret_cast<const float4*>(sK + g * 512)[lane];
            const float4 kn = reinterpret_cast<const float4*>(sK + g * 512 + 256)[lane];

            const float4* mrel4 = reinterpret_cast<const float4*>(mrel0) + (size_t)bg * 2048;
            const float4* drel4 = reinterpret_cast<const float4*>(drel0) + (size_t)bg * 2048;
            const float4* mnod4 = reinterpret_cast<const float4*>(mnode1) + (size_t)bg * 2048;
            const float4* dnod4 = reinterpret_cast<const float4*>(dnode1) + (size_t)bg * 2048;

            float m = -3.0e38f, l = 0.f;
            float ar0 = 0, ar1 = 0, ar2 = 0, ar3 = 0;
            float an0 = 0, an1 = 0, an2 = 0, an3 = 0;

            float4 rv = mrel4[lane];
            float4 nv = mnod4[lane];
            for (int n = 0; n < 64; ++n) {
                float4 rv_n = rv, nv_n = nv;
                if (n + 1 < 64) {                 // prefetch next neighbor row
                    const int np = n + 1;
                    rv_n = (np < 32) ? mrel4[np * 64 + lane] : drel4[(np - 32) * 64 + lane];
                    nv_n = (np < 32) ? mnod4[np * 64 + lane] : dnod4[(np - 32) * 64 + lane];
                }
                float p = rv.x * kr.x + rv.y * kr.y + rv.z * kr.z + rv.w * kr.w
                        + nv.x * kn.x + nv.y * kn.y + nv.z * kn.z + nv.w * kn.w;
                #pragma unroll
                for (int off = 32; off >= 1; off >>= 1) p += __shfl_xor(p, off);
                const float s    = (p + sb) * 0.0625f;   // / sqrt(256)
                const float mnew = fmaxf(m, s);
                const float esc  = __expf(m - mnew);
                const float wn   = __expf(s - mnew);
                l = l * esc + wn;
                ar0 = ar0 * esc + wn * rv.x;  ar1 = ar1 * esc + wn * rv.y;
                ar2 = ar2 * esc + wn * rv.z;  ar3 = ar3 * esc + wn * rv.w;
                an0 = an0 * esc + wn * nv.x;  an1 = an1 * esc + wn * nv.y;
                an2 = an2 * esc + wn * nv.z;  an3 = an3 * esc + wn * nv.w;
                m = mnew;
                rv = rv_n; nv = nv_n;
            }
            const float inv = 1.f / l;
            reinterpret_cast<float4*>(sA + g * 512)[lane] =
                make_float4(ar0 * inv, ar1 * inv, ar2 * inv, ar3 * inv);
            reinterpret_cast<float4*>(sA + g * 512 + 256)[lane] =
                make_float4(an0 * inv, an1 * inv, an2 * inv, an3 * inv);
        }
    }
    __syncthreads();

    // ---------- Phase 6: local = wsum @ Wv + bv ----------
    #pragma unroll
    for (int g = 0; g < G; ++g) acc[g] = 0.f;
    #pragma unroll 4
    for (int i4 = 0; i4 < 128; ++i4) {
        const float w0 = Wv[(i4 * 4 + 0) * 256 + t];
        const float w1 = Wv[(i4 * 4 + 1) * 256 + t];
        const float w2 = Wv[(i4 * 4 + 2) * 256 + t];
        const float w3 = Wv[(i4 * 4 + 3) * 256 + t];
        #pragma unroll
        for (int g = 0; g < G; ++g) {
            const float4 a = reinterpret_cast<const float4*>(sA)[g * 128 + i4];
            acc[g] = fmaf(a.x, w0, fmaf(a.y, w1, fmaf(a.z, w2, fmaf(a.w, w3, acc[g]))));
        }
    }
    {
        const float bvv = bv[t];
        #pragma unroll
        for (int g = 0; g < G; ++g)
            out[(size_t)(b0 + g) * 512 + 256 + t] = acc[g] + bvv;   // output[:, 256:512]
    }
}

extern "C" void kernel_launch(void* const* d_in, const int* in_sizes, int n_in,
                              void* d_out, int out_size, void* d_ws, size_t ws_size,
                              hipStream_t stream) {
    const float* mnode0 = (const float*)d_in[0];
    const float* mnode1 = (const float*)d_in[1];
    const float* dnode0 = (const float*)d_in[2];
    const float* dnode1 = (const float*)d_in[3];
    const float* mrel0  = (const float*)d_in[4];
    const float* drel0  = (const float*)d_in[5];
    const float* W_edge = (const float*)d_in[6];
    const float* b_edge = (const float*)d_in[7];
    const float* Wq     = (const float*)d_in[8];
    const float* bq     = (const float*)d_in[9];
    const float* Wk     = (const float*)d_in[10];
    const float* bk     = (const float*)d_in[11];
    const float* Wv     = (const float*)d_in[12];
    const float* bv     = (const float*)d_in[13];
    float* out = (float*)d_out;

    superedge_fused<<<dim3(8192 / G), dim3(256), 0, stream>>>(
        mnode0, mnode1, dnode0, dnode1, mrel0, drel0,
        W_edge, b_edge, Wq, bq, Wk, bk, Wv, bv, out);
}